// Round 8
// baseline (244.803 us; speedup 1.0000x reference)
//
#include <hip/hip_runtime.h>

// ---------------- types / helpers ----------------
typedef unsigned short u16;
typedef float f32x4 __attribute__((ext_vector_type(4)));
typedef short bf16x8 __attribute__((ext_vector_type(8)));
typedef short bf16x4 __attribute__((ext_vector_type(4)));

__device__ __forceinline__ u16 f2bf(float f) {
    unsigned u = __float_as_uint(f);
    u = (u + 0x7FFFu + ((u >> 16) & 1u)) >> 16;
    return (u16)u;
}

#define LOG2E 1.4426950408889634f

#if __has_builtin(__builtin_amdgcn_exp2f)
__device__ __forceinline__ float exp2_fast(float x) { return __builtin_amdgcn_exp2f(x); }
#else
__device__ __forceinline__ float exp2_fast(float x) { return __expf(x * 0.6931471805599453f); }
#endif

// pack two fp32 -> (bf16(b)<<16)|bf16(a), round-half-up
__device__ __forceinline__ unsigned pack2bf(float a, float b) {
    unsigned ua = __float_as_uint(a) + 0x8000u;
    unsigned ub = __float_as_uint(b) + 0x8000u;
#if __has_builtin(__builtin_amdgcn_perm)
    return __builtin_amdgcn_perm(ub, ua, 0x07060302u);
#else
    return ((ua >> 16) & 0xFFFFu) | (ub & 0xFFFF0000u);
#endif
}

// single-instruction packed fp32x2 -> bf16x2 (gfx950 v_cvt_pk_bf16_f32), RNE
#if __has_builtin(__builtin_amdgcn_cvt_pk_bf16_f32)
typedef __bf16 bf2_t __attribute__((ext_vector_type(2)));
__device__ __forceinline__ unsigned cvtpk(float a, float b) {
    bf2_t r = __builtin_amdgcn_cvt_pk_bf16_f32(a, b);
    return __builtin_bit_cast(unsigned, r);
}
#else
__device__ __forceinline__ unsigned cvtpk(float a, float b) { return pack2bf(a, b); }
#endif

__device__ __forceinline__ bf16x4 bc4(uint2 u) { return __builtin_bit_cast(bf16x4, u); }
__device__ __forceinline__ bf16x8 bc8(uint4 u) { return __builtin_bit_cast(bf16x8, u); }

// PV MFMA: 16x16x16 bf16 (K=16). A[m=lane&15][k=quad*4+j], B[k=quad*4+j][n=lane&15].
#if __has_builtin(__builtin_amdgcn_mfma_f32_16x16x16bf16_1k)
__device__ __forceinline__ f32x4 pv_mfma(bf16x4 a, bf16x4 b, f32x4 c) {
    return __builtin_amdgcn_mfma_f32_16x16x16bf16_1k(a, b, c, 0, 0, 0);
}
#elif __has_builtin(__builtin_amdgcn_mfma_f32_16x16x16_bf16)
__device__ __forceinline__ f32x4 pv_mfma(bf16x4 a, bf16x4 b, f32x4 c) {
    return __builtin_amdgcn_mfma_f32_16x16x16_bf16(a, b, c, 0, 0, 0);
}
#else
// Exact fallback: 16x16x32 with zero-padded high halves.
__device__ __forceinline__ f32x4 pv_mfma(bf16x4 a, bf16x4 b, f32x4 c) {
    bf16x8 a8 = {a[0], a[1], a[2], a[3], 0, 0, 0, 0};
    bf16x8 b8 = {b[0], b[1], b[2], b[3], 0, 0, 0, 0};
    return __builtin_amdgcn_mfma_f32_16x16x32_bf16(a8, b8, c, 0, 0, 0);
}
#endif

// Problem constants
#define BB 2
#define HH 56
#define CC 256
#define NH 8
#define DK 32
#define SQ 3136          // 56*56
#define HP 62
#define SK 3844          // 62*62
#define VT_STRIDE 3856   // padded row stride for Vt (16B-aligned rows)

// workspace offsets (u16 units); total 5,548,032 u16 = 11.1 MB
#define WS_Q    0         // 6272*256
#define WS_K    1605632   // 7688*256
#define WS_VT   3573760   // 512*3856

// ---------------- kernel 1: projections; weight transpose + reflect-pad fused ----------------
// grid (121, 3 modes, 2 n-halves). mode: 0=Q (M=6272), 1=K, 2=V-transposed (M=7688).
// Each block transposes its own 128-col weight slice from fp32 W (L2-hot) per k-step.
#define BSTR 40
__global__ __launch_bounds__(256, 4) void proj_kernel(const float* __restrict__ x,
                                                      const float* __restrict__ Wq,
                                                      const float* __restrict__ Wk,
                                                      const float* __restrict__ Wv,
                                                      const float* __restrict__ bq,
                                                      const float* __restrict__ bk,
                                                      const float* __restrict__ bv,
                                                      u16* __restrict__ qout,
                                                      u16* __restrict__ kout,
                                                      u16* __restrict__ vtout) {
    __shared__ __align__(16) u16 Bl[128 * BSTR];

    int mode  = blockIdx.y;
    int nz    = blockIdx.z;
    int mbase = blockIdx.x * 64;
    int M = (mode == 0) ? (BB * SQ) : (BB * SK);
    if (mbase >= M) return;
    int tid = threadIdx.x;
    int wave = tid >> 6, lane = tid & 63, quad = lane >> 4, l16 = lane & 15;

    const float* W = (mode == 0) ? Wq : ((mode == 1) ? Wk : Wv);
    const float* bias = (mode == 0) ? bq : ((mode == 1) ? bk : bv);
    float wscale = (mode == 0) ? LOG2E : 1.0f;

    int m_a = mbase + wave * 16 + l16;           // A-fragment row
    if (m_a >= M) m_a = M - 1;
    int xrow;
    if (mode == 0) {
        xrow = m_a;                              // Q: interior rows are x rows directly
    } else {
        int b = (m_a >= SK) ? 1 : 0;
        int sp = m_a - b * SK;
        int hp = sp / HP, wp = sp - hp * HP;
        int hs = hp - 3; hs = hs < 0 ? -hs : (hs >= HH ? 110 - hs : hs);
        int ws_ = wp - 3; ws_ = ws_ < 0 ? -ws_ : (ws_ >= HH ? 110 - ws_ : ws_);
        xrow = b * SQ + hs * HH + ws_;
    }
    const float* xr = x + (size_t)xrow * 256;

    // weight staging role: thread owns k-row kq, 16 cols cb..cb+15
    int kq = tid >> 3;          // 0..31
    int cb = (tid & 7) * 16;    // 0..112

    f32x4 acc[8];
#pragma unroll
    for (int i = 0; i < 8; i++) acc[i] = (f32x4){0.f, 0.f, 0.f, 0.f};

    float4 wreg[4];
    auto wload = [&](int s) {
        const float* p = W + (size_t)(s * 32 + kq) * 256 + nz * 128 + cb;
        wreg[0] = *(const float4*)&p[0];
        wreg[1] = *(const float4*)&p[4];
        wreg[2] = *(const float4*)&p[8];
        wreg[3] = *(const float4*)&p[12];
    };
    auto wwrite = [&]() {
#pragma unroll
        for (int i = 0; i < 16; i++) {
            float v = ((const float*)wreg)[i] * wscale;
            Bl[(cb + i) * BSTR + kq] = f2bf(v);
        }
    };

    wload(0);
    for (int s = 0; s < 8; ++s) {
        int kk = s * 32;
        wwrite();
        __syncthreads();
        if (s < 7) wload(s + 1);
        // A-frag: 8 contiguous fp32 channels -> bf16x8 in registers
        float4 f0 = *(const float4*)&xr[kk + quad * 8];
        float4 f1 = *(const float4*)&xr[kk + quad * 8 + 4];
        uint4 aw = (uint4){pack2bf(f0.x, f0.y), pack2bf(f0.z, f0.w),
                           pack2bf(f1.x, f1.y), pack2bf(f1.z, f1.w)};
        bf16x8 afrag = bc8(aw);
#pragma unroll
        for (int nt = 0; nt < 8; nt++) {
            bf16x8 bfrag = *(const bf16x8*)&Bl[(nt * 16 + l16) * BSTR + quad * 8];
            acc[nt] = __builtin_amdgcn_mfma_f32_16x16x32_bf16(afrag, bfrag, acc[nt], 0, 0, 0);
        }
        __syncthreads();
    }

    // epilogue: C/D layout row = quad*4+reg, col = lane&15
    int mrow_base = mbase + wave * 16 + quad * 4;
    if (mode == 2) {
#pragma unroll
        for (int nt = 0; nt < 8; nt++) {
            int c = nz * 128 + nt * 16 + l16;
            float bvv = bias[c];
#pragma unroll
            for (int p = 0; p < 4; p += 2) {
                int m = mrow_base + p;
                if (m + 1 < M) {
                    int bb = (m >= SK) ? 1 : 0;
                    int kp = m - bb * SK;
                    unsigned pk = pack2bf(acc[nt][p] + bvv, acc[nt][p + 1] + bvv);
                    *(unsigned*)&vtout[(size_t)(bb * 256 + c) * VT_STRIDE + kp] = pk;
                }
            }
        }
    } else {
#pragma unroll
        for (int r = 0; r < 4; r++) {
            int m = mrow_base + r;
            if (m >= M) continue;
#pragma unroll
            for (int nt = 0; nt < 8; nt++) {
                int c = nz * 128 + nt * 16 + l16;
                float v = acc[nt][r] + bias[c] * ((mode == 0) ? LOG2E : 1.0f);
                u16 hv = f2bf(v);
                if (mode == 0) qout[((size_t)m << 8) + c] = hv;
                else           kout[((size_t)m << 8) + c] = hv;
            }
        }
    }
}

// ---------------- kernel 2: flash attention (fixed m=0), in-block key split ----------------
// grid (49 q-tiles, 16 b*h), 256 thr = 4 waves. Block owns 64 queries x ALL keys.
// wave w: qs=w&1 -> queries qs*32..+31; half=w>>1 -> key chunks half*16.. (16/15 chunks).
// Each wave-pair stages its own K/V stream; halves merge in-block via LDS; epilogue
// writes final gamma*O/l + x straight to out. No atomics, no extra kernels.
#define KSTR 40
#define VSTR 136
__global__ __launch_bounds__(256, 2) void attn_kernel(const u16* __restrict__ qb,
                                                      const u16* __restrict__ kb,
                                                      const u16* __restrict__ vtb,
                                                      const float* __restrict__ x,
                                                      const float* __restrict__ gammap,
                                                      float* __restrict__ out) {
    __shared__ __align__(16) u16 K_lds[2][128 * KSTR];   // per key-half stream
    __shared__ __align__(16) u16 V_lds[2][32 * VSTR];

    int tid = threadIdx.x;
    int wave = tid >> 6, lane = tid & 63, quad = lane >> 4, l16 = lane & 15;
    int half = wave >> 1, qs = wave & 1;
    int stid = tid & 127;                 // staging id within wave-pair
    int bh = blockIdx.y;
    int b = bh >> 3, h = bh & 7;
    int qsub = blockIdx.x * 64 + qs * 32;
    int rounds = half ? 15 : 16;          // chunks: half*16 + r, 31 total

    // Q B-fragments (16x16x32): n = l16 -> query, k = quad*8+j
    bf16x8 qf0 = *(const bf16x8*)&qb[((size_t)(b * SQ + qsub + l16) << 8) + h * 32 + quad * 8];
    bf16x8 qf1 = *(const bf16x8*)&qb[((size_t)(b * SQ + qsub + 16 + l16) << 8) + h * 32 + quad * 8];

    const u16* kg = kb + ((size_t)(b * SK) << 8) + h * 32;
    const u16* vg = vtb + (size_t)(b * 256 + h * 32) * VT_STRIDE;

    u16* Kl = K_lds[half];
    u16* Vl = V_lds[half];

    f32x4 o00{0.f,0.f,0.f,0.f}, o01{0.f,0.f,0.f,0.f};
    f32x4 o10{0.f,0.f,0.f,0.f}, o11{0.f,0.f,0.f,0.f};
    f32x4 l0{0.f,0.f,0.f,0.f},  l1{0.f,0.f,0.f,0.f};

    // ones B-frag (16x16x16): B[k][n=0]=1 -> lanes with l16==0 hold ones
    short ov = (l16 == 0) ? (short)0x3F80 : (short)0;
    bf16x4 ones4 = {ov, ov, ov, ov};

    // staging: 128 threads per stream; K 8KB + V 8KB per chunk = 4+4 uint4/thread
    uint4 kr[4], vr[4];
    auto prefetch = [&](int rr) {
        int ka = (half * 16 + rr) * 128;
#pragma unroll
        for (int i = 0; i < 4; i++) {
            int seg = i * 128 + stid;
            int row = seg >> 2, part = seg & 3;
            int g = ka + row; if (g > SK - 1) g = SK - 1;
            kr[i] = *(const uint4*)&kg[((size_t)g << 8) + part * 8];
            int vrow = seg >> 4, c16 = seg & 15;
            int c = ka + c16 * 8; if (c > VT_STRIDE - 8) c = VT_STRIDE - 8;
            vr[i] = *(const uint4*)&vg[(size_t)vrow * VT_STRIDE + c];
        }
    };
    auto writeAll = [&]() {
#pragma unroll
        for (int i = 0; i < 4; i++) {
            int seg = i * 128 + stid;
            *(uint4*)&Kl[(seg >> 2) * KSTR + (seg & 3) * 8] = kr[i];
            *(uint4*)&Vl[(seg >> 4) * VSTR + (seg & 15) * 8] = vr[i];
        }
    };

    prefetch(0);
    writeAll();
    __syncthreads();
    prefetch(1);

    for (int r = 0; r < 16; ++r) {
        if (r < rounds) {
            int ch = half * 16 + r;
            bool tail = (ch == 30);
#pragma unroll
            for (int t = 0; t < 8; ++t) {
                bf16x8 kf = *(const bf16x8*)&Kl[(t * 16 + l16) * KSTR + quad * 8];
                f32x4 e0 = __builtin_amdgcn_mfma_f32_16x16x32_bf16(kf, qf0, (f32x4){0.f,0.f,0.f,0.f}, 0, 0, 0);
                f32x4 e1 = __builtin_amdgcn_mfma_f32_16x16x32_bf16(kf, qf1, (f32x4){0.f,0.f,0.f,0.f}, 0, 0, 0);
                float p0[4], p1[4];
                if (tail) {
                    int kb0 = ch * 128 + t * 16 + quad * 4;
#pragma unroll
                    for (int j = 0; j < 4; ++j) {
                        bool valid = (kb0 + j) < SK;
                        p0[j] = valid ? exp2_fast(e0[j]) : 0.f;
                        p1[j] = valid ? exp2_fast(e1[j]) : 0.f;
                    }
                } else {
#pragma unroll
                    for (int j = 0; j < 4; ++j) {
                        p0[j] = exp2_fast(e0[j]);
                        p1[j] = exp2_fast(e1[j]);
                    }
                }
                bf16x4 pa0 = bc4((uint2){cvtpk(p0[0], p0[1]), cvtpk(p0[2], p0[3])});
                bf16x4 pa1 = bc4((uint2){cvtpk(p1[0], p1[1]), cvtpk(p1[2], p1[3])});
                uint2 w0 = *(const uint2*)&Vl[l16 * VSTR + t * 16 + quad * 4];
                uint2 w1 = *(const uint2*)&Vl[(16 + l16) * VSTR + t * 16 + quad * 4];
                bf16x4 vb0 = bc4(w0), vb1 = bc4(w1);
                o00 = pv_mfma(pa0, vb0, o00);
                o01 = pv_mfma(pa0, vb1, o01);
                o10 = pv_mfma(pa1, vb0, o10);
                o11 = pv_mfma(pa1, vb1, o11);
                l0  = pv_mfma(pa0, ones4, l0);
                l1  = pv_mfma(pa1, ones4, l1);
            }
        }
        __syncthreads();                     // all reads of this round done
        if (r < rounds - 1) writeAll();      // write next round's chunk
        __syncthreads();                     // writes visible
        if (r < rounds - 2) prefetch(r + 2);
    }

    // ---- merge key-halves via LDS (exact fp32 sums; fixed m=0) ----
    float* mg = (float*)&K_lds[0][0];        // 12.3 KB scratch in dead 20.5 KB K region
    int slot = (qs * 64 + lane) * 24;
    if (half == 1) {
        *(f32x4*)&mg[slot + 0]  = o00;
        *(f32x4*)&mg[slot + 4]  = o01;
        *(f32x4*)&mg[slot + 8]  = o10;
        *(f32x4*)&mg[slot + 12] = o11;
        *(f32x4*)&mg[slot + 16] = l0;
        *(f32x4*)&mg[slot + 20] = l1;
    }
    __syncthreads();
    if (half == 0) {
        o00 += *(const f32x4*)&mg[slot + 0];
        o01 += *(const f32x4*)&mg[slot + 4];
        o10 += *(const f32x4*)&mg[slot + 8];
        o11 += *(const f32x4*)&mg[slot + 12];
        l0  += *(const f32x4*)&mg[slot + 16];
        l1  += *(const f32x4*)&mg[slot + 20];

        float g = gammap[0];
#pragma unroll
        for (int r2 = 0; r2 < 4; ++r2) {
            float inv0 = g / __shfl(l0[r2], quad * 16);   // col 0 of own quad holds l
            float inv1 = g / __shfl(l1[r2], quad * 16);
            size_t base0 = (size_t)(b * SQ + qsub + quad * 4 + r2) * 256 + h * 32;
            size_t base1 = base0 + (size_t)16 * 256;
            out[base0 + l16]      = o00[r2] * inv0 + x[base0 + l16];
            out[base0 + 16 + l16] = o01[r2] * inv0 + x[base0 + 16 + l16];
            out[base1 + l16]      = o10[r2] * inv1 + x[base1 + l16];
            out[base1 + 16 + l16] = o11[r2] * inv1 + x[base1 + 16 + l16];
        }
    }
}

// ---------------- launcher ----------------
extern "C" void kernel_launch(void* const* d_in, const int* in_sizes, int n_in,
                              void* d_out, int out_size, void* d_ws, size_t ws_size,
                              hipStream_t stream) {
    const float* x     = (const float*)d_in[0];
    const float* Wq    = (const float*)d_in[1];
    const float* bq    = (const float*)d_in[2];
    const float* Wk    = (const float*)d_in[3];
    const float* bk    = (const float*)d_in[4];
    const float* Wv    = (const float*)d_in[5];
    const float* bv    = (const float*)d_in[6];
    const float* gamma = (const float*)d_in[7];
    float* out = (float*)d_out;

    u16* ws   = (u16*)d_ws;
    u16* qbuf = ws + WS_Q;
    u16* kbuf = ws + WS_K;
    u16* vtb  = ws + WS_VT;

    proj_kernel<<<dim3(121, 3, 2), 256, 0, stream>>>(x, Wq, Wk, Wv, bq, bk, bv,
                                                     qbuf, kbuf, vtb);
    attn_kernel<<<dim3(49, 16), 256, 0, stream>>>(qbuf, kbuf, vtb, x, gamma, out);
}

// Round 9
// 170.790 us; speedup vs baseline: 1.4334x; 1.4334x over previous
//
#include <hip/hip_runtime.h>

// ---------------- types / helpers ----------------
typedef unsigned short u16;
typedef float f32x4 __attribute__((ext_vector_type(4)));
typedef short bf16x8 __attribute__((ext_vector_type(8)));
typedef short bf16x4 __attribute__((ext_vector_type(4)));

__device__ __forceinline__ u16 f2bf(float f) {
    unsigned u = __float_as_uint(f);
    u = (u + 0x7FFFu + ((u >> 16) & 1u)) >> 16;
    return (u16)u;
}

#define LOG2E 1.4426950408889634f

#if __has_builtin(__builtin_amdgcn_exp2f)
__device__ __forceinline__ float exp2_fast(float x) { return __builtin_amdgcn_exp2f(x); }
#else
__device__ __forceinline__ float exp2_fast(float x) { return __expf(x * 0.6931471805599453f); }
#endif

// pack two fp32 -> (bf16(b)<<16)|bf16(a), round-half-up
__device__ __forceinline__ unsigned pack2bf(float a, float b) {
    unsigned ua = __float_as_uint(a) + 0x8000u;
    unsigned ub = __float_as_uint(b) + 0x8000u;
#if __has_builtin(__builtin_amdgcn_perm)
    return __builtin_amdgcn_perm(ub, ua, 0x07060302u);
#else
    return ((ua >> 16) & 0xFFFFu) | (ub & 0xFFFF0000u);
#endif
}

// single-instruction packed fp32x2 -> bf16x2 (gfx950 v_cvt_pk_bf16_f32), RNE
#if __has_builtin(__builtin_amdgcn_cvt_pk_bf16_f32)
typedef __bf16 bf2_t __attribute__((ext_vector_type(2)));
__device__ __forceinline__ unsigned cvtpk(float a, float b) {
    bf2_t r = __builtin_amdgcn_cvt_pk_bf16_f32(a, b);
    return __builtin_bit_cast(unsigned, r);
}
#else
__device__ __forceinline__ unsigned cvtpk(float a, float b) { return pack2bf(a, b); }
#endif

__device__ __forceinline__ bf16x4 bc4(uint2 u) { return __builtin_bit_cast(bf16x4, u); }
__device__ __forceinline__ bf16x8 bc8(uint4 u) { return __builtin_bit_cast(bf16x8, u); }

// async 16B/lane global->LDS DMA. DMA semantics: lds dst = uniform base + lane*16.
// Fallback replicates exactly (lane passed for that purpose).
#if __has_builtin(__builtin_amdgcn_global_load_lds)
typedef const __attribute__((address_space(1))) void* as1cv;
typedef __attribute__((address_space(3))) void* as3v;
__device__ __forceinline__ void dma16(const void* g, void* lds_base, int lane) {
    __builtin_amdgcn_global_load_lds((as1cv)g, (as3v)lds_base, 16, 0, 0);
}
#else
__device__ __forceinline__ void dma16(const void* g, void* lds_base, int lane) {
    *(uint4*)((char*)lds_base + lane * 16) = *(const uint4*)g;
}
#endif

// PV MFMA: 16x16x16 bf16 (K=16). A[m=lane&15][k=quad*4+j], B[k=quad*4+j][n=lane&15].
#if __has_builtin(__builtin_amdgcn_mfma_f32_16x16x16bf16_1k)
__device__ __forceinline__ f32x4 pv_mfma(bf16x4 a, bf16x4 b, f32x4 c) {
    return __builtin_amdgcn_mfma_f32_16x16x16bf16_1k(a, b, c, 0, 0, 0);
}
#elif __has_builtin(__builtin_amdgcn_mfma_f32_16x16x16_bf16)
__device__ __forceinline__ f32x4 pv_mfma(bf16x4 a, bf16x4 b, f32x4 c) {
    return __builtin_amdgcn_mfma_f32_16x16x16_bf16(a, b, c, 0, 0, 0);
}
#else
// Exact fallback: 16x16x32 with zero-padded high halves.
__device__ __forceinline__ f32x4 pv_mfma(bf16x4 a, bf16x4 b, f32x4 c) {
    bf16x8 a8 = {a[0], a[1], a[2], a[3], 0, 0, 0, 0};
    bf16x8 b8 = {b[0], b[1], b[2], b[3], 0, 0, 0, 0};
    return __builtin_amdgcn_mfma_f32_16x16x32_bf16(a8, b8, c, 0, 0, 0);
}
#endif

// Problem constants
#define BB 2
#define HH 56
#define CC 256
#define NH 8
#define DK 32
#define SQ 3136          // 56*56
#define HP 62
#define SK 3844          // 62*62
#define VT_STRIDE 3856   // padded row stride for Vt (16B-aligned rows)

// workspace offsets (u16 units); total 5,548,032 u16 = 11.1 MB
#define WS_Q    0         // 6272*256
#define WS_K    1605632   // 7688*256
#define WS_VT   3573760   // 512*3856

// ---------------- kernel 1: projections; weight transpose + reflect-pad fused ----------------
// grid (121, 3 modes, 2 n-halves). mode: 0=Q (M=6272), 1=K, 2=V-transposed (M=7688).
#define BSTR 40
__global__ __launch_bounds__(256, 4) void proj_kernel(const float* __restrict__ x,
                                                      const float* __restrict__ Wq,
                                                      const float* __restrict__ Wk,
                                                      const float* __restrict__ Wv,
                                                      const float* __restrict__ bq,
                                                      const float* __restrict__ bk,
                                                      const float* __restrict__ bv,
                                                      u16* __restrict__ qout,
                                                      u16* __restrict__ kout,
                                                      u16* __restrict__ vtout) {
    __shared__ __align__(16) u16 Bl[128 * BSTR];

    int mode  = blockIdx.y;
    int nz    = blockIdx.z;
    int mbase = blockIdx.x * 64;
    int M = (mode == 0) ? (BB * SQ) : (BB * SK);
    if (mbase >= M) return;
    int tid = threadIdx.x;
    int wave = tid >> 6, lane = tid & 63, quad = lane >> 4, l16 = lane & 15;

    const float* W = (mode == 0) ? Wq : ((mode == 1) ? Wk : Wv);
    const float* bias = (mode == 0) ? bq : ((mode == 1) ? bk : bv);
    float wscale = (mode == 0) ? LOG2E : 1.0f;

    int m_a = mbase + wave * 16 + l16;           // A-fragment row
    if (m_a >= M) m_a = M - 1;
    int xrow;
    if (mode == 0) {
        xrow = m_a;                              // Q: interior rows are x rows directly
    } else {
        int b = (m_a >= SK) ? 1 : 0;
        int sp = m_a - b * SK;
        int hp = sp / HP, wp = sp - hp * HP;
        int hs = hp - 3; hs = hs < 0 ? -hs : (hs >= HH ? 110 - hs : hs);
        int ws_ = wp - 3; ws_ = ws_ < 0 ? -ws_ : (ws_ >= HH ? 110 - ws_ : ws_);
        xrow = b * SQ + hs * HH + ws_;
    }
    const float* xr = x + (size_t)xrow * 256;

    // weight staging role: thread owns k-row kq, 16 cols cb..cb+15
    int kq = tid >> 3;          // 0..31
    int cb = (tid & 7) * 16;    // 0..112

    f32x4 acc[8];
#pragma unroll
    for (int i = 0; i < 8; i++) acc[i] = (f32x4){0.f, 0.f, 0.f, 0.f};

    float4 wreg[4];
    auto wload = [&](int s) {
        const float* p = W + (size_t)(s * 32 + kq) * 256 + nz * 128 + cb;
        wreg[0] = *(const float4*)&p[0];
        wreg[1] = *(const float4*)&p[4];
        wreg[2] = *(const float4*)&p[8];
        wreg[3] = *(const float4*)&p[12];
    };
    auto wwrite = [&]() {
#pragma unroll
        for (int i = 0; i < 16; i++) {
            float v = ((const float*)wreg)[i] * wscale;
            Bl[(cb + i) * BSTR + kq] = f2bf(v);
        }
    };

    wload(0);
    for (int s = 0; s < 8; ++s) {
        int kk = s * 32;
        wwrite();
        __syncthreads();
        if (s < 7) wload(s + 1);
        float4 f0 = *(const float4*)&xr[kk + quad * 8];
        float4 f1 = *(const float4*)&xr[kk + quad * 8 + 4];
        uint4 aw = (uint4){pack2bf(f0.x, f0.y), pack2bf(f0.z, f0.w),
                           pack2bf(f1.x, f1.y), pack2bf(f1.z, f1.w)};
        bf16x8 afrag = bc8(aw);
#pragma unroll
        for (int nt = 0; nt < 8; nt++) {
            bf16x8 bfrag = *(const bf16x8*)&Bl[(nt * 16 + l16) * BSTR + quad * 8];
            acc[nt] = __builtin_amdgcn_mfma_f32_16x16x32_bf16(afrag, bfrag, acc[nt], 0, 0, 0);
        }
        __syncthreads();
    }

    // epilogue: C/D layout row = quad*4+reg, col = lane&15
    int mrow_base = mbase + wave * 16 + quad * 4;
    if (mode == 2) {
#pragma unroll
        for (int nt = 0; nt < 8; nt++) {
            int c = nz * 128 + nt * 16 + l16;
            float bvv = bias[c];
#pragma unroll
            for (int p = 0; p < 4; p += 2) {
                int m = mrow_base + p;
                if (m + 1 < M) {
                    int bb = (m >= SK) ? 1 : 0;
                    int kp = m - bb * SK;
                    unsigned pk = pack2bf(acc[nt][p] + bvv, acc[nt][p + 1] + bvv);
                    *(unsigned*)&vtout[(size_t)(bb * 256 + c) * VT_STRIDE + kp] = pk;
                }
            }
        }
    } else {
#pragma unroll
        for (int r = 0; r < 4; r++) {
            int m = mrow_base + r;
            if (m >= M) continue;
#pragma unroll
            for (int nt = 0; nt < 8; nt++) {
                int c = nz * 128 + nt * 16 + l16;
                float v = acc[nt][r] + bias[c] * ((mode == 0) ? LOG2E : 1.0f);
                u16 hv = f2bf(v);
                if (mode == 0) qout[((size_t)m << 8) + c] = hv;
                else           kout[((size_t)m << 8) + c] = hv;
            }
        }
    }
}

// ---------------- kernel 2: flash attention (fixed m=0), DMA double-buffered ----------------
// grid (49, 16), 256 thr = 4 waves. wave w: qs=w&1 -> 32 queries; half=w>>1 -> key chunks.
// Staging via global_load_lds with per-lane address swizzles giving conflict-free reads:
//  K chunk (8KB): group t (1KB) holds unit (quad*16+l16) = K[key t*16+l16][dk quad*8..+7]
//  V chunk (8KB): pos (k8*32+row)  = Vt[dk row][keys k8*8..+7]
// LDS = 2 streams x 2 bufs x 16KB = 64KB; one barrier per round; merge via LDS scratch.
__global__ __launch_bounds__(256, 2) void attn_kernel(const u16* __restrict__ qb,
                                                      const u16* __restrict__ kb,
                                                      const u16* __restrict__ vtb,
                                                      const float* __restrict__ x,
                                                      const float* __restrict__ gammap,
                                                      float* __restrict__ out) {
    __shared__ __align__(16) u16 S[32768];   // 64KB: [(stream*2+buf)*8192], K +0, V +4096

    int tid = threadIdx.x;
    int wave = tid >> 6, lane = tid & 63, quad = lane >> 4, l16 = lane & 15;
    int half = wave >> 1, qs = wave & 1;
    int bh = blockIdx.y;
    int b = bh >> 3, h = bh & 7;
    int qsub = blockIdx.x * 64 + qs * 32;
    int rounds = half ? 15 : 16;             // stream chunk counts (31 total)

    // Q B-fragments (16x16x32): n = l16 -> query, k = quad*8+j
    bf16x8 qf0 = *(const bf16x8*)&qb[((size_t)(b * SQ + qsub + l16) << 8) + h * 32 + quad * 8];
    bf16x8 qf1 = *(const bf16x8*)&qb[((size_t)(b * SQ + qsub + 16 + l16) << 8) + h * 32 + quad * 8];

    const u16* kg = kb + ((size_t)(b * SK) << 8) + h * 32;
    const u16* vg = vtb + (size_t)(b * 256 + h * 32) * VT_STRIDE;

    f32x4 o00{0.f,0.f,0.f,0.f}, o01{0.f,0.f,0.f,0.f};
    f32x4 o10{0.f,0.f,0.f,0.f}, o11{0.f,0.f,0.f,0.f};
    f32x4 l0{0.f,0.f,0.f,0.f},  l1{0.f,0.f,0.f,0.f};

    // ones B-frag (16x16x16): B[k][n=0]=1 -> lanes with l16==0 hold ones
    short ov = (l16 == 0) ? (short)0x3F80 : (short)0;
    bf16x4 ones4 = {ov, ov, ov, ov};

    // DMA staging: wave qs==0 issues K (8 calls), qs==1 issues V (8 calls), own stream.
    // K lane roles: grow-in-group = lane&15, part = lane>>4.
    // V lane roles: row = lane&31, k8loc = lane>>5.
    auto stage = [&](int r_ch, int buf) {
        u16* base = &S[(half * 2 + buf) * 8192];
        int kbase = (half * 16 + r_ch) * 128;
        if (qs == 0) {
#pragma unroll
            for (int t = 0; t < 8; ++t) {
                int grow = kbase + t * 16 + (lane & 15);
                if (grow > SK - 1) grow = SK - 1;
                const u16* g = kg + ((size_t)grow << 8) + (lane >> 4) * 8;
                dma16(g, base + t * 512, lane);
            }
        } else {
#pragma unroll
            for (int j = 0; j < 8; ++j) {
                int row = lane & 31;
                int col = kbase + (2 * j + (lane >> 5)) * 8;
                if (col > VT_STRIDE - 8) col = VT_STRIDE - 8;
                const u16* g = vg + (size_t)row * VT_STRIDE + col;
                dma16(g, base + 4096 + j * 512, lane);
            }
        }
    };

    stage(0, 0);
    __syncthreads();             // drains chunk-0 DMA (vmcnt(0) before barrier)
    stage(1, 1);                 // in flight during round 0

    for (int r = 0; r < 16; ++r) {
        if (r < rounds) {
            const u16* Kl = &S[(half * 2 + (r & 1)) * 8192];
            const u16* Vl = Kl + 4096;
            int ch = half * 16 + r;
            bool tail = (ch == 30);
#pragma unroll
            for (int t = 0; t < 8; ++t) {
                bf16x8 kf = *(const bf16x8*)&Kl[t * 512 + ((quad << 4) + l16) * 8];
                f32x4 e0 = __builtin_amdgcn_mfma_f32_16x16x32_bf16(kf, qf0, (f32x4){0.f,0.f,0.f,0.f}, 0, 0, 0);
                f32x4 e1 = __builtin_amdgcn_mfma_f32_16x16x32_bf16(kf, qf1, (f32x4){0.f,0.f,0.f,0.f}, 0, 0, 0);
                float p0[4], p1[4];
                if (tail) {
                    int kb0 = ch * 128 + t * 16 + quad * 4;
#pragma unroll
                    for (int j = 0; j < 4; ++j) {
                        bool valid = (kb0 + j) < SK;
                        p0[j] = valid ? exp2_fast(e0[j]) : 0.f;
                        p1[j] = valid ? exp2_fast(e1[j]) : 0.f;
                    }
                } else {
#pragma unroll
                    for (int j = 0; j < 4; ++j) {
                        p0[j] = exp2_fast(e0[j]);
                        p1[j] = exp2_fast(e1[j]);
                    }
                }
                bf16x4 pa0 = bc4((uint2){cvtpk(p0[0], p0[1]), cvtpk(p0[2], p0[3])});
                bf16x4 pa1 = bc4((uint2){cvtpk(p1[0], p1[1]), cvtpk(p1[2], p1[3])});
                int vbase = ((2 * t + (quad >> 1)) << 5) * 8 + (quad & 1) * 4;
                uint2 w0 = *(const uint2*)&Vl[vbase + l16 * 8];
                uint2 w1 = *(const uint2*)&Vl[vbase + (16 + l16) * 8];
                bf16x4 vb0 = bc4(w0), vb1 = bc4(w1);
                o00 = pv_mfma(pa0, vb0, o00);
                o01 = pv_mfma(pa0, vb1, o01);
                o10 = pv_mfma(pa1, vb0, o10);
                o11 = pv_mfma(pa1, vb1, o11);
                l0  = pv_mfma(pa0, ones4, l0);
                l1  = pv_mfma(pa1, ones4, l1);
            }
        }
        __syncthreads();                       // drains DMA(r+1); frees buf r&1
        if (r + 2 < rounds) stage(r + 2, r & 1);
    }

    // ---- merge key-halves via LDS scratch (first 12KB of stream-0 region; DMA-quiet) ----
    float* mg = (float*)&S[0];
    int slot = (qs * 64 + lane) * 24;
    if (half == 1) {
        *(f32x4*)&mg[slot + 0]  = o00;
        *(f32x4*)&mg[slot + 4]  = o01;
        *(f32x4*)&mg[slot + 8]  = o10;
        *(f32x4*)&mg[slot + 12] = o11;
        *(f32x4*)&mg[slot + 16] = l0;
        *(f32x4*)&mg[slot + 20] = l1;
    }
    __syncthreads();
    if (half == 0) {
        o00 += *(const f32x4*)&mg[slot + 0];
        o01 += *(const f32x4*)&mg[slot + 4];
        o10 += *(const f32x4*)&mg[slot + 8];
        o11 += *(const f32x4*)&mg[slot + 12];
        l0  += *(const f32x4*)&mg[slot + 16];
        l1  += *(const f32x4*)&mg[slot + 20];

        float g = gammap[0];
#pragma unroll
        for (int r2 = 0; r2 < 4; ++r2) {
            float inv0 = g / __shfl(l0[r2], quad * 16);   // col 0 of own quad holds l
            float inv1 = g / __shfl(l1[r2], quad * 16);
            size_t base0 = (size_t)(b * SQ + qsub + quad * 4 + r2) * 256 + h * 32;
            size_t base1 = base0 + (size_t)16 * 256;
            out[base0 + l16]      = o00[r2] * inv0 + x[base0 + l16];
            out[base0 + 16 + l16] = o01[r2] * inv0 + x[base0 + 16 + l16];
            out[base1 + l16]      = o10[r2] * inv1 + x[base1 + l16];
            out[base1 + 16 + l16] = o11[r2] * inv1 + x[base1 + 16 + l16];
        }
    }
}

// ---------------- launcher ----------------
extern "C" void kernel_launch(void* const* d_in, const int* in_sizes, int n_in,
                              void* d_out, int out_size, void* d_ws, size_t ws_size,
                              hipStream_t stream) {
    const float* x     = (const float*)d_in[0];
    const float* Wq    = (const float*)d_in[1];
    const float* bq    = (const float*)d_in[2];
    const float* Wk    = (const float*)d_in[3];
    const float* bk    = (const float*)d_in[4];
    const float* Wv    = (const float*)d_in[5];
    const float* bv    = (const float*)d_in[6];
    const float* gamma = (const float*)d_in[7];
    float* out = (float*)d_out;

    u16* ws   = (u16*)d_ws;
    u16* qbuf = ws + WS_Q;
    u16* kbuf = ws + WS_K;
    u16* vtb  = ws + WS_VT;

    proj_kernel<<<dim3(121, 3, 2), 256, 0, stream>>>(x, Wq, Wk, Wv, bq, bk, bv,
                                                     qbuf, kbuf, vtb);
    attn_kernel<<<dim3(49, 16), 256, 0, stream>>>(qbuf, kbuf, vtb, x, gamma, out);
}

// Round 10
// 156.965 us; speedup vs baseline: 1.5596x; 1.0881x over previous
//
#include <hip/hip_runtime.h>

// ---------------- types / helpers ----------------
typedef unsigned short u16;
typedef float f32x4 __attribute__((ext_vector_type(4)));
typedef short bf16x8 __attribute__((ext_vector_type(8)));
typedef short bf16x4 __attribute__((ext_vector_type(4)));

__device__ __forceinline__ u16 f2bf(float f) {
    unsigned u = __float_as_uint(f);
    u = (u + 0x7FFFu + ((u >> 16) & 1u)) >> 16;
    return (u16)u;
}

#define LOG2E 1.4426950408889634f

#if __has_builtin(__builtin_amdgcn_exp2f)
__device__ __forceinline__ float exp2_fast(float x) { return __builtin_amdgcn_exp2f(x); }
#else
__device__ __forceinline__ float exp2_fast(float x) { return __expf(x * 0.6931471805599453f); }
#endif

__device__ __forceinline__ unsigned pack2bf(float a, float b) {
    unsigned ua = __float_as_uint(a) + 0x8000u;
    unsigned ub = __float_as_uint(b) + 0x8000u;
#if __has_builtin(__builtin_amdgcn_perm)
    return __builtin_amdgcn_perm(ub, ua, 0x07060302u);
#else
    return ((ua >> 16) & 0xFFFFu) | (ub & 0xFFFF0000u);
#endif
}

#if __has_builtin(__builtin_amdgcn_cvt_pk_bf16_f32)
typedef __bf16 bf2_t __attribute__((ext_vector_type(2)));
__device__ __forceinline__ unsigned cvtpk(float a, float b) {
    bf2_t r = __builtin_amdgcn_cvt_pk_bf16_f32(a, b);
    return __builtin_bit_cast(unsigned, r);
}
#else
__device__ __forceinline__ unsigned cvtpk(float a, float b) { return pack2bf(a, b); }
#endif

__device__ __forceinline__ bf16x4 bc4(uint2 u) { return __builtin_bit_cast(bf16x4, u); }
__device__ __forceinline__ bf16x8 bc8(uint4 u) { return __builtin_bit_cast(bf16x8, u); }

// async 16B/lane global->LDS DMA; lds dst = wave-uniform base + lane*16.
#if __has_builtin(__builtin_amdgcn_global_load_lds)
typedef const __attribute__((address_space(1))) void* as1cv;
typedef __attribute__((address_space(3))) void* as3v;
__device__ __forceinline__ void dma16(const void* g, void* lds_base, int lane) {
    __builtin_amdgcn_global_load_lds((as1cv)g, (as3v)lds_base, 16, 0, 0);
}
#else
__device__ __forceinline__ void dma16(const void* g, void* lds_base, int lane) {
    *(uint4*)((char*)lds_base + lane * 16) = *(const uint4*)g;
}
#endif

// PV MFMA: 16x16x16 bf16. A[m=lane&15][k=quad*4+j], B[k=quad*4+j][n=lane&15].
#if __has_builtin(__builtin_amdgcn_mfma_f32_16x16x16bf16_1k)
__device__ __forceinline__ f32x4 pv_mfma(bf16x4 a, bf16x4 b, f32x4 c) {
    return __builtin_amdgcn_mfma_f32_16x16x16bf16_1k(a, b, c, 0, 0, 0);
}
#elif __has_builtin(__builtin_amdgcn_mfma_f32_16x16x16_bf16)
__device__ __forceinline__ f32x4 pv_mfma(bf16x4 a, bf16x4 b, f32x4 c) {
    return __builtin_amdgcn_mfma_f32_16x16x16_bf16(a, b, c, 0, 0, 0);
}
#else
__device__ __forceinline__ f32x4 pv_mfma(bf16x4 a, bf16x4 b, f32x4 c) {
    bf16x8 a8 = {a[0], a[1], a[2], a[3], 0, 0, 0, 0};
    bf16x8 b8 = {b[0], b[1], b[2], b[3], 0, 0, 0, 0};
    return __builtin_amdgcn_mfma_f32_16x16x32_bf16(a8, b8, c, 0, 0, 0);
}
#endif

// Problem constants
#define BB 2
#define HH 56
#define CC 256
#define NH 8
#define DK 32
#define SQ 3136
#define HP 62
#define SK 3844
#define VT_STRIDE 3856

// workspace offsets (u16 units); total 5,648,384 u16 = 11.3 MB
#define WS_Q    0         // 6272*256
#define WS_K    1605632   // 7688*256
#define WS_VT   3573760   // 512*3856
#define WS_LB   5548032   // 50176 floats

#define NZERO_F4 413952   // (6272*256 + 6272*8)/4 float4 slots

// ---------------- kernel 1: projections (+ zero out/lbuf for attn atomics) ----------------
// grid (121, 3 modes, 2 n-halves). mode: 0=Q (M=6272), 1=K, 2=V-transposed (M=7688).
#define BSTR 40
__global__ __launch_bounds__(256, 4) void proj_kernel(const float* __restrict__ x,
                                                      const float* __restrict__ Wq,
                                                      const float* __restrict__ Wk,
                                                      const float* __restrict__ Wv,
                                                      const float* __restrict__ bq,
                                                      const float* __restrict__ bk,
                                                      const float* __restrict__ bv,
                                                      u16* __restrict__ qout,
                                                      u16* __restrict__ kout,
                                                      u16* __restrict__ vtout,
                                                      float* __restrict__ out,
                                                      float* __restrict__ lbuf) {
    __shared__ __align__(16) u16 Bl[128 * BSTR];

    int mode  = blockIdx.y;
    int nz    = blockIdx.z;
    int mbase = blockIdx.x * 64;
    int tid = threadIdx.x;

    // zero out (1,605,632 f) + lbuf (50,176 f) across all 726 blocks, float4
    {
        int gid = ((blockIdx.z * 3 + blockIdx.y) * 121 + blockIdx.x) * 256 + tid;
        const int n_out4 = (SQ * BB * CC) / 4;
        for (int i = gid; i < NZERO_F4; i += 726 * 256) {
            if (i < n_out4) *(float4*)&out[i * 4] = (float4){0.f, 0.f, 0.f, 0.f};
            else            *(float4*)&lbuf[(i - n_out4) * 4] = (float4){0.f, 0.f, 0.f, 0.f};
        }
    }

    int M = (mode == 0) ? (BB * SQ) : (BB * SK);
    if (mbase >= M) return;
    int wave = tid >> 6, lane = tid & 63, quad = lane >> 4, l16 = lane & 15;

    const float* W = (mode == 0) ? Wq : ((mode == 1) ? Wk : Wv);
    const float* bias = (mode == 0) ? bq : ((mode == 1) ? bk : bv);
    float wscale = (mode == 0) ? LOG2E : 1.0f;

    int m_a = mbase + wave * 16 + l16;
    if (m_a >= M) m_a = M - 1;
    int xrow;
    if (mode == 0) {
        xrow = m_a;
    } else {
        int b = (m_a >= SK) ? 1 : 0;
        int sp = m_a - b * SK;
        int hp = sp / HP, wp = sp - hp * HP;
        int hs = hp - 3; hs = hs < 0 ? -hs : (hs >= HH ? 110 - hs : hs);
        int ws_ = wp - 3; ws_ = ws_ < 0 ? -ws_ : (ws_ >= HH ? 110 - ws_ : ws_);
        xrow = b * SQ + hs * HH + ws_;
    }
    const float* xr = x + (size_t)xrow * 256;

    int kq = tid >> 3;          // k-row 0..31
    int cb = (tid & 7) * 16;    // col base

    f32x4 acc[8];
#pragma unroll
    for (int i = 0; i < 8; i++) acc[i] = (f32x4){0.f, 0.f, 0.f, 0.f};

    float4 wreg[4];
    auto wload = [&](int s) {
        const float* p = W + (size_t)(s * 32 + kq) * 256 + nz * 128 + cb;
        wreg[0] = *(const float4*)&p[0];
        wreg[1] = *(const float4*)&p[4];
        wreg[2] = *(const float4*)&p[8];
        wreg[3] = *(const float4*)&p[12];
    };
    auto wwrite = [&]() {
#pragma unroll
        for (int i = 0; i < 16; i++) {
            float v = ((const float*)wreg)[i] * wscale;
            Bl[(cb + i) * BSTR + kq] = f2bf(v);
        }
    };

    wload(0);
    for (int s = 0; s < 8; ++s) {
        int kk = s * 32;
        wwrite();
        __syncthreads();
        if (s < 7) wload(s + 1);
        float4 f0 = *(const float4*)&xr[kk + quad * 8];
        float4 f1 = *(const float4*)&xr[kk + quad * 8 + 4];
        uint4 aw = (uint4){pack2bf(f0.x, f0.y), pack2bf(f0.z, f0.w),
                           pack2bf(f1.x, f1.y), pack2bf(f1.z, f1.w)};
        bf16x8 afrag = bc8(aw);
#pragma unroll
        for (int nt = 0; nt < 8; nt++) {
            bf16x8 bfrag = *(const bf16x8*)&Bl[(nt * 16 + l16) * BSTR + quad * 8];
            acc[nt] = __builtin_amdgcn_mfma_f32_16x16x32_bf16(afrag, bfrag, acc[nt], 0, 0, 0);
        }
        __syncthreads();
    }

    int mrow_base = mbase + wave * 16 + quad * 4;
    if (mode == 2) {
#pragma unroll
        for (int nt = 0; nt < 8; nt++) {
            int c = nz * 128 + nt * 16 + l16;
            float bvv = bias[c];
#pragma unroll
            for (int p = 0; p < 4; p += 2) {
                int m = mrow_base + p;
                if (m + 1 < M) {
                    int bb = (m >= SK) ? 1 : 0;
                    int kp = m - bb * SK;
                    unsigned pk = pack2bf(acc[nt][p] + bvv, acc[nt][p + 1] + bvv);
                    *(unsigned*)&vtout[(size_t)(bb * 256 + c) * VT_STRIDE + kp] = pk;
                }
            }
        }
    } else {
#pragma unroll
        for (int r = 0; r < 4; r++) {
            int m = mrow_base + r;
            if (m >= M) continue;
#pragma unroll
            for (int nt = 0; nt < 8; nt++) {
                int c = nz * 128 + nt * 16 + l16;
                float v = acc[nt][r] + bias[c] * ((mode == 0) ? LOG2E : 1.0f);
                u16 hv = f2bf(v);
                if (mode == 0) qout[((size_t)m << 8) + c] = hv;
                else           kout[((size_t)m << 8) + c] = hv;
            }
        }
    }
}

// ---------------- kernel 2: flash attention (fixed m=0) ----------------
// grid (49, 16, 2 key-halves), 256 thr = 4 waves sharing ONE key stream.
// wave w: qs=w&1 -> 32 queries (qs*32); th=w>>1 -> keys t=th*4..+3 of each 128-chunk.
// LDS: 2 bufs x (8KB K + 8KB V) = 32KB, DMA double-buffered, 1 barrier/round.
// In-block t-half merge via LDS; cross-block 2-way merge via fp32 atomicAdd into out.
__global__ __launch_bounds__(256) void attn_kernel(const u16* __restrict__ qb,
                                                   const u16* __restrict__ kb,
                                                   const u16* __restrict__ vtb,
                                                   float* __restrict__ out,
                                                   float* __restrict__ lbuf) {
    __shared__ __align__(16) u16 S[16384];   // buf b at b*8192: K +0, V +4096

    int tid = threadIdx.x;
    int wave = tid >> 6, lane = tid & 63, quad = lane >> 4, l16 = lane & 15;
    int qs = wave & 1, th = wave >> 1;
    int bh = blockIdx.y;
    int b = bh >> 3, h = bh & 7;
    int half = blockIdx.z;
    int qsub = blockIdx.x * 64 + qs * 32;
    int rounds = half ? 15 : 16;             // chunks half*16 + r (31 total)

    // Q B-fragments (16x16x32): n=l16 -> query, k=quad*8+j
    bf16x8 qf0 = *(const bf16x8*)&qb[((size_t)(b * SQ + qsub + l16) << 8) + h * 32 + quad * 8];
    bf16x8 qf1 = *(const bf16x8*)&qb[((size_t)(b * SQ + qsub + 16 + l16) << 8) + h * 32 + quad * 8];

    const u16* kg = kb + ((size_t)(b * SK) << 8) + h * 32;
    const u16* vg = vtb + (size_t)(b * 256 + h * 32) * VT_STRIDE;

    f32x4 o00{0.f,0.f,0.f,0.f}, o01{0.f,0.f,0.f,0.f};
    f32x4 o10{0.f,0.f,0.f,0.f}, o11{0.f,0.f,0.f,0.f};
    f32x4 l0{0.f,0.f,0.f,0.f},  l1{0.f,0.f,0.f,0.f};

    short ov = (l16 == 0) ? (short)0x3F80 : (short)0;
    bf16x4 ones4 = {ov, ov, ov, ov};

    // staging: wave w issues K groups {w, w+4} and V groups {w, w+4} (4 dma16/thread).
    // K group t (1KB): lane unit = K[key t*16+(lane&15)][dk (lane>>4)*8..+7]
    // V group j (1KB): lane = Vt[dk lane&31][keys (2j+(lane>>5))*8..+7]
    auto stage = [&](int r_ch, int buf) {
        u16* base = &S[buf * 8192];
        int kbase = (half * 16 + r_ch) * 128;
#pragma unroll
        for (int i = 0; i < 2; ++i) {
            int g = wave + i * 4;
            int grow = kbase + g * 16 + (lane & 15);
            if (grow > SK - 1) grow = SK - 1;
            dma16(kg + ((size_t)grow << 8) + (lane >> 4) * 8, base + g * 512, lane);
            int col = kbase + (2 * g + (lane >> 5)) * 8;
            if (col > VT_STRIDE - 8) col = VT_STRIDE - 8;
            dma16(vg + (size_t)(lane & 31) * VT_STRIDE + col, base + 4096 + g * 512, lane);
        }
    };

    stage(0, 0);
    __syncthreads();              // drains chunk-0 DMA
    stage(1, 1);                  // in flight during round 0

    for (int r = 0; r < 16; ++r) {
        if (r < rounds) {
            const u16* Kl = &S[(r & 1) * 8192];
            const u16* Vl = Kl + 4096;
            int ch = half * 16 + r;
            bool tail = (ch == 30);
#pragma unroll
            for (int tt = 0; tt < 4; ++tt) {
                int t = th * 4 + tt;
                bf16x8 kf = *(const bf16x8*)&Kl[t * 512 + ((quad << 4) + l16) * 8];
                f32x4 e0 = __builtin_amdgcn_mfma_f32_16x16x32_bf16(kf, qf0, (f32x4){0.f,0.f,0.f,0.f}, 0, 0, 0);
                f32x4 e1 = __builtin_amdgcn_mfma_f32_16x16x32_bf16(kf, qf1, (f32x4){0.f,0.f,0.f,0.f}, 0, 0, 0);
                float p0[4], p1[4];
                if (tail) {
                    int kb0 = ch * 128 + t * 16 + quad * 4;
#pragma unroll
                    for (int j = 0; j < 4; ++j) {
                        bool valid = (kb0 + j) < SK;
                        p0[j] = valid ? exp2_fast(e0[j]) : 0.f;
                        p1[j] = valid ? exp2_fast(e1[j]) : 0.f;
                    }
                } else {
#pragma unroll
                    for (int j = 0; j < 4; ++j) {
                        p0[j] = exp2_fast(e0[j]);
                        p1[j] = exp2_fast(e1[j]);
                    }
                }
                bf16x4 pa0 = bc4((uint2){cvtpk(p0[0], p0[1]), cvtpk(p0[2], p0[3])});
                bf16x4 pa1 = bc4((uint2){cvtpk(p1[0], p1[1]), cvtpk(p1[2], p1[3])});
                int vbase = ((2 * t + (quad >> 1)) << 8) + (quad & 1) * 4;
                uint2 w0 = *(const uint2*)&Vl[vbase + l16 * 8];
                uint2 w1 = *(const uint2*)&Vl[vbase + (16 + l16) * 8];
                bf16x4 vb0 = bc4(w0), vb1 = bc4(w1);
                o00 = pv_mfma(pa0, vb0, o00);
                o01 = pv_mfma(pa0, vb1, o01);
                o10 = pv_mfma(pa1, vb0, o10);
                o11 = pv_mfma(pa1, vb1, o11);
                l0  = pv_mfma(pa0, ones4, l0);
                l1  = pv_mfma(pa1, ones4, l1);
            }
        }
        __syncthreads();                       // drains DMA(r+1); frees buf r&1
        if (r + 2 < rounds) stage(r + 2, r & 1);
    }

    // ---- in-block merge of t-halves via LDS (DMA quiet after final barrier) ----
    float* mg = (float*)&S[0];                 // 12 KB scratch
    int slot = (qs * 64 + lane) * 24;
    if (th == 1) {
        *(f32x4*)&mg[slot + 0]  = o00;
        *(f32x4*)&mg[slot + 4]  = o01;
        *(f32x4*)&mg[slot + 8]  = o10;
        *(f32x4*)&mg[slot + 12] = o11;
        *(f32x4*)&mg[slot + 16] = l0;
        *(f32x4*)&mg[slot + 20] = l1;
    }
    __syncthreads();
    if (th == 0) {
        o00 += *(const f32x4*)&mg[slot + 0];
        o01 += *(const f32x4*)&mg[slot + 4];
        o10 += *(const f32x4*)&mg[slot + 8];
        o11 += *(const f32x4*)&mg[slot + 12];
        l0  += *(const f32x4*)&mg[slot + 16];
        l1  += *(const f32x4*)&mg[slot + 20];

        // ---- cross-block 2-way merge: fp32 atomics (device-scope) ----
#pragma unroll
        for (int r2 = 0; r2 < 4; ++r2) {
            int q0 = qsub + quad * 4 + r2;
            int q1 = q0 + 16;
            size_t base0 = (size_t)(b * SQ + q0) * 256 + h * 32;
            size_t base1 = (size_t)(b * SQ + q1) * 256 + h * 32;
            atomicAdd(&out[base0 + l16],      o00[r2]);
            atomicAdd(&out[base0 + 16 + l16], o01[r2]);
            atomicAdd(&out[base1 + l16],      o10[r2]);
            atomicAdd(&out[base1 + 16 + l16], o11[r2]);
            if (l16 == 0) {
                atomicAdd(&lbuf[(b * SQ + q0) * 8 + h], l0[r2]);
                atomicAdd(&lbuf[(b * SQ + q1) * 8 + h], l1[r2]);
            }
        }
    }
}

// ---------------- kernel 3: finalize out = gamma * O / l + x ----------------
__global__ __launch_bounds__(256) void finalize_kernel(const float* __restrict__ x,
                                                       const float* __restrict__ gammap,
                                                       const float* __restrict__ lbuf,
                                                       float* __restrict__ out) {
    int gid = blockIdx.x * 256 + threadIdx.x;   // 6272*64 threads, float4 each
    int row = gid >> 6;
    int c4  = (gid & 63) << 2;
    int h   = c4 >> 5;
    float g = gammap[0];
    float linv = g / lbuf[row * 8 + h];
    size_t base = (size_t)row * 256 + c4;
    float4 o = *(const float4*)&out[base];
    float4 xv = *(const float4*)&x[base];
    o.x = o.x * linv + xv.x;
    o.y = o.y * linv + xv.y;
    o.z = o.z * linv + xv.z;
    o.w = o.w * linv + xv.w;
    *(float4*)&out[base] = o;
}

// ---------------- launcher ----------------
extern "C" void kernel_launch(void* const* d_in, const int* in_sizes, int n_in,
                              void* d_out, int out_size, void* d_ws, size_t ws_size,
                              hipStream_t stream) {
    const float* x     = (const float*)d_in[0];
    const float* Wq    = (const float*)d_in[1];
    const float* bq    = (const float*)d_in[2];
    const float* Wk    = (const float*)d_in[3];
    const float* bk    = (const float*)d_in[4];
    const float* Wv    = (const float*)d_in[5];
    const float* bv    = (const float*)d_in[6];
    const float* gamma = (const float*)d_in[7];
    float* out = (float*)d_out;

    u16* ws   = (u16*)d_ws;
    u16* qbuf = ws + WS_Q;
    u16* kbuf = ws + WS_K;
    u16* vtb  = ws + WS_VT;
    float* lbuf = (float*)(ws + WS_LB);

    proj_kernel<<<dim3(121, 3, 2), 256, 0, stream>>>(x, Wq, Wk, Wv, bq, bk, bv,
                                                     qbuf, kbuf, vtb, out, lbuf);
    attn_kernel<<<dim3(49, 16, 2), 256, 0, stream>>>(qbuf, kbuf, vtb, out, lbuf);
    finalize_kernel<<<1568, 256, 0, stream>>>(x, gamma, lbuf, out);
}

// Round 12
// 156.949 us; speedup vs baseline: 1.5598x; 1.0001x over previous
//
#include <hip/hip_runtime.h>

// ---------------- types / helpers ----------------
typedef unsigned short u16;
typedef float f32x4 __attribute__((ext_vector_type(4)));
typedef short bf16x8 __attribute__((ext_vector_type(8)));
typedef short bf16x4 __attribute__((ext_vector_type(4)));

__device__ __forceinline__ u16 f2bf(float f) {
    unsigned u = __float_as_uint(f);
    u = (u + 0x7FFFu + ((u >> 16) & 1u)) >> 16;
    return (u16)u;
}

#define LOG2E 1.4426950408889634f

#if __has_builtin(__builtin_amdgcn_exp2f)
__device__ __forceinline__ float exp2_fast(float x) { return __builtin_amdgcn_exp2f(x); }
#else
__device__ __forceinline__ float exp2_fast(float x) { return __expf(x * 0.6931471805599453f); }
#endif

__device__ __forceinline__ unsigned pack2bf(float a, float b) {
    unsigned ua = __float_as_uint(a) + 0x8000u;
    unsigned ub = __float_as_uint(b) + 0x8000u;
#if __has_builtin(__builtin_amdgcn_perm)
    return __builtin_amdgcn_perm(ub, ua, 0x07060302u);
#else
    return ((ua >> 16) & 0xFFFFu) | (ub & 0xFFFF0000u);
#endif
}

#if __has_builtin(__builtin_amdgcn_cvt_pk_bf16_f32)
typedef __bf16 bf2_t __attribute__((ext_vector_type(2)));
__device__ __forceinline__ unsigned cvtpk(float a, float b) {
    bf2_t r = __builtin_amdgcn_cvt_pk_bf16_f32(a, b);
    return __builtin_bit_cast(unsigned, r);
}
#else
__device__ __forceinline__ unsigned cvtpk(float a, float b) { return pack2bf(a, b); }
#endif

__device__ __forceinline__ bf16x4 bc4(uint2 u) { return __builtin_bit_cast(bf16x4, u); }
__device__ __forceinline__ bf16x8 bc8(uint4 u) { return __builtin_bit_cast(bf16x8, u); }

// async 16B/lane global->LDS DMA; lds dst = wave-uniform base + lane*16.
#if __has_builtin(__builtin_amdgcn_global_load_lds)
typedef const __attribute__((address_space(1))) void* as1cv;
typedef __attribute__((address_space(3))) void* as3v;
__device__ __forceinline__ void dma16(const void* g, void* lds_base, int lane) {
    __builtin_amdgcn_global_load_lds((as1cv)g, (as3v)lds_base, 16, 0, 0);
}
#else
__device__ __forceinline__ void dma16(const void* g, void* lds_base, int lane) {
    *(uint4*)((char*)lds_base + lane * 16) = *(const uint4*)g;
}
#endif

// PV MFMA: 16x16x16 bf16. A[m=lane&15][k=quad*4+j], B[k=quad*4+j][n=lane&15].
#if __has_builtin(__builtin_amdgcn_mfma_f32_16x16x16bf16_1k)
__device__ __forceinline__ f32x4 pv_mfma(bf16x4 a, bf16x4 b, f32x4 c) {
    return __builtin_amdgcn_mfma_f32_16x16x16bf16_1k(a, b, c, 0, 0, 0);
}
#elif __has_builtin(__builtin_amdgcn_mfma_f32_16x16x16_bf16)
__device__ __forceinline__ f32x4 pv_mfma(bf16x4 a, bf16x4 b, f32x4 c) {
    return __builtin_amdgcn_mfma_f32_16x16x16_bf16(a, b, c, 0, 0, 0);
}
#else
__device__ __forceinline__ f32x4 pv_mfma(bf16x4 a, bf16x4 b, f32x4 c) {
    bf16x8 a8 = {a[0], a[1], a[2], a[3], 0, 0, 0, 0};
    bf16x8 b8 = {b[0], b[1], b[2], b[3], 0, 0, 0, 0};
    return __builtin_amdgcn_mfma_f32_16x16x32_bf16(a8, b8, c, 0, 0, 0);
}
#endif

// Problem constants
#define BB 2
#define HH 56
#define CC 256
#define NH 8
#define DK 32
#define SQ 3136
#define HP 62
#define SK 3844
#define VT_STRIDE 3856

// workspace offsets (u16 units); total 5,648,384 u16 = 11.3 MB
#define WS_Q    0         // 6272*256
#define WS_K    1605632   // 7688*256
#define WS_VT   3573760   // 512*3856
#define WS_LB   5548032   // 50176 floats

#define NZERO_F4 413952   // (6272*256 + 6272*8)/4 float4 slots

// ---------------- kernel 1: projections (+ zero out/lbuf for attn atomics) ----------------
// grid (121, 3 modes, 2 n-halves). mode: 0=Q (M=6272), 1=K, 2=V-transposed (M=7688).
#define BSTR 40
__global__ __launch_bounds__(256, 4) void proj_kernel(const float* __restrict__ x,
                                                      const float* __restrict__ Wq,
                                                      const float* __restrict__ Wk,
                                                      const float* __restrict__ Wv,
                                                      const float* __restrict__ bq,
                                                      const float* __restrict__ bk,
                                                      const float* __restrict__ bv,
                                                      u16* __restrict__ qout,
                                                      u16* __restrict__ kout,
                                                      u16* __restrict__ vtout,
                                                      float* __restrict__ out,
                                                      float* __restrict__ lbuf) {
    __shared__ __align__(16) u16 Bl[128 * BSTR];

    int mode  = blockIdx.y;
    int nz    = blockIdx.z;
    int mbase = blockIdx.x * 64;
    int tid = threadIdx.x;

    // zero out (1,605,632 f) + lbuf (50,176 f) across all 726 blocks, float4
    {
        int gid = ((blockIdx.z * 3 + blockIdx.y) * 121 + blockIdx.x) * 256 + tid;
        const int n_out4 = (SQ * BB * CC) / 4;
        for (int i = gid; i < NZERO_F4; i += 726 * 256) {
            if (i < n_out4) *(float4*)&out[i * 4] = (float4){0.f, 0.f, 0.f, 0.f};
            else            *(float4*)&lbuf[(i - n_out4) * 4] = (float4){0.f, 0.f, 0.f, 0.f};
        }
    }

    int M = (mode == 0) ? (BB * SQ) : (BB * SK);
    if (mbase >= M) return;
    int wave = tid >> 6, lane = tid & 63, quad = lane >> 4, l16 = lane & 15;

    const float* W = (mode == 0) ? Wq : ((mode == 1) ? Wk : Wv);
    const float* bias = (mode == 0) ? bq : ((mode == 1) ? bk : bv);
    float wscale = (mode == 0) ? LOG2E : 1.0f;

    int m_a = mbase + wave * 16 + l16;
    if (m_a >= M) m_a = M - 1;
    int xrow;
    if (mode == 0) {
        xrow = m_a;
    } else {
        int b = (m_a >= SK) ? 1 : 0;
        int sp = m_a - b * SK;
        int hp = sp / HP, wp = sp - hp * HP;
        int hs = hp - 3; hs = hs < 0 ? -hs : (hs >= HH ? 110 - hs : hs);
        int ws_ = wp - 3; ws_ = ws_ < 0 ? -ws_ : (ws_ >= HH ? 110 - ws_ : ws_);
        xrow = b * SQ + hs * HH + ws_;
    }
    const float* xr = x + (size_t)xrow * 256;

    int kq = tid >> 3;          // k-row 0..31
    int cb = (tid & 7) * 16;    // col base

    f32x4 acc[8];
#pragma unroll
    for (int i = 0; i < 8; i++) acc[i] = (f32x4){0.f, 0.f, 0.f, 0.f};

    float4 wreg[4];
    auto wload = [&](int s) {
        const float* p = W + (size_t)(s * 32 + kq) * 256 + nz * 128 + cb;
        wreg[0] = *(const float4*)&p[0];
        wreg[1] = *(const float4*)&p[4];
        wreg[2] = *(const float4*)&p[8];
        wreg[3] = *(const float4*)&p[12];
    };

    wload(0);
    for (int s = 0; s < 8; ++s) {
        int kk = s * 32;
#pragma unroll
        for (int i = 0; i < 16; i++) {
            float v = ((const float*)wreg)[i] * wscale;
            Bl[(cb + i) * BSTR + kq] = f2bf(v);
        }
        __syncthreads();
        if (s < 7) wload(s + 1);
        float4 f0 = *(const float4*)&xr[kk + quad * 8];
        float4 f1 = *(const float4*)&xr[kk + quad * 8 + 4];
        uint4 aw = (uint4){pack2bf(f0.x, f0.y), pack2bf(f0.z, f0.w),
                           pack2bf(f1.x, f1.y), pack2bf(f1.z, f1.w)};
        bf16x8 afrag = bc8(aw);
#pragma unroll
        for (int nt = 0; nt < 8; nt++) {
            bf16x8 bfrag = *(const bf16x8*)&Bl[(nt * 16 + l16) * BSTR + quad * 8];
            acc[nt] = __builtin_amdgcn_mfma_f32_16x16x32_bf16(afrag, bfrag, acc[nt], 0, 0, 0);
        }
        __syncthreads();
    }

    int mrow_base = mbase + wave * 16 + quad * 4;
    if (mode == 2) {
#pragma unroll
        for (int nt = 0; nt < 8; nt++) {
            int c = nz * 128 + nt * 16 + l16;
            float bvv = bias[c];
#pragma unroll
            for (int p = 0; p < 4; p += 2) {
                int m = mrow_base + p;
                if (m + 1 < M) {
                    int bb = (m >= SK) ? 1 : 0;
                    int kp = m - bb * SK;
                    unsigned pk = pack2bf(acc[nt][p] + bvv, acc[nt][p + 1] + bvv);
                    *(unsigned*)&vtout[(size_t)(bb * 256 + c) * VT_STRIDE + kp] = pk;
                }
            }
        }
    } else {
#pragma unroll
        for (int r = 0; r < 4; r++) {
            int m = mrow_base + r;
            if (m >= M) continue;
#pragma unroll
            for (int nt = 0; nt < 8; nt++) {
                int c = nz * 128 + nt * 16 + l16;
                float v = acc[nt][r] + bias[c] * ((mode == 0) ? LOG2E : 1.0f);
                u16 hv = f2bf(v);
                if (mode == 0) qout[((size_t)m << 8) + c] = hv;
                else           kout[((size_t)m << 8) + c] = hv;
            }
        }
    }
}

// ---------------- kernel 2: flash attention (fixed m=0) ----------------
// grid (49, 16, 2 key-halves), 256 thr = 4 waves sharing ONE key stream.
// EACH WAVE owns ALL 64 queries (4 Q-frags) and a t-QUARTER of keys (t = th, th+4):
// K/V LDS reads amortize over 2x queries vs R10; 4 independent chains per wave.
// LDS: 2 bufs x (8KB K + 8KB V) = 32KB, DMA double-buffered, 1 barrier/round.
// Two-stage in-block t-merge; cross-block 2-way merge via fp32 atomicAdd into out.
__global__ __launch_bounds__(256, 4) void attn_kernel(const u16* __restrict__ qb,
                                                      const u16* __restrict__ kb,
                                                      const u16* __restrict__ vtb,
                                                      float* __restrict__ out,
                                                      float* __restrict__ lbuf) {
    __shared__ __align__(16) u16 S[16384];   // buf b at b*8192: K +0, V +4096

    int tid = threadIdx.x;
    int th = tid >> 6, lane = tid & 63, quad = lane >> 4, l16 = lane & 15;
    int bh = blockIdx.y;
    int b = bh >> 3, h = bh & 7;
    int half = blockIdx.z;
    int qsub = blockIdx.x * 64;
    int rounds = half ? 15 : 16;             // chunks half*16 + r (31 total)

    // 4 Q B-fragments (16x16x32): n=l16 -> query qsub+i*16+l16, k=quad*8+j
    bf16x8 qf[4];
#pragma unroll
    for (int i = 0; i < 4; ++i)
        qf[i] = *(const bf16x8*)&qb[((size_t)(b * SQ + qsub + i * 16 + l16) << 8) + h * 32 + quad * 8];

    const u16* kg = kb + ((size_t)(b * SK) << 8) + h * 32;
    const u16* vg = vtb + (size_t)(b * 256 + h * 32) * VT_STRIDE;

    f32x4 o[4][2], lv[4];
#pragma unroll
    for (int i = 0; i < 4; ++i) {
        o[i][0] = (f32x4){0.f,0.f,0.f,0.f};
        o[i][1] = (f32x4){0.f,0.f,0.f,0.f};
        lv[i]   = (f32x4){0.f,0.f,0.f,0.f};
    }

    short ov = (l16 == 0) ? (short)0x3F80 : (short)0;
    bf16x4 ones4 = {ov, ov, ov, ov};

    // staging: wave th issues K groups {th, th+4} and V groups {th, th+4}.
    // K group t (1KB): lane = K[key t*16+(lane&15)][dk (lane>>4)*8..+7]
    // V group j (1KB): lane = Vt[dk lane&31][keys (2j+(lane>>5))*8..+7]
    auto stage = [&](int r_ch, int buf) {
        u16* base = &S[buf * 8192];
        int kbase = (half * 16 + r_ch) * 128;
#pragma unroll
        for (int i = 0; i < 2; ++i) {
            int g = th + i * 4;
            int grow = kbase + g * 16 + (lane & 15);
            if (grow > SK - 1) grow = SK - 1;
            dma16(kg + ((size_t)grow << 8) + (lane >> 4) * 8, base + g * 512, lane);
            int col = kbase + (2 * g + (lane >> 5)) * 8;
            if (col > VT_STRIDE - 8) col = VT_STRIDE - 8;
            dma16(vg + (size_t)(lane & 31) * VT_STRIDE + col, base + 4096 + g * 512, lane);
        }
    };

    stage(0, 0);
    __syncthreads();              // drains chunk-0 DMA
    stage(1, 1);                  // in flight during round 0

    for (int r = 0; r < rounds; ++r) {
        const u16* Kl = &S[(r & 1) * 8192];
        const u16* Vl = Kl + 4096;
        int ch = half * 16 + r;
        bool tail = (ch == 30);
#pragma unroll
        for (int tt = 0; tt < 2; ++tt) {
            int t = th + tt * 4;
            bf16x8 kf = *(const bf16x8*)&Kl[t * 512 + ((quad << 4) + l16) * 8];
            f32x4 e[4];
#pragma unroll
            for (int i = 0; i < 4; ++i)
                e[i] = __builtin_amdgcn_mfma_f32_16x16x32_bf16(kf, qf[i], (f32x4){0.f,0.f,0.f,0.f}, 0, 0, 0);
            bf16x4 pa[4];
            if (tail) {
                int kb0 = ch * 128 + t * 16 + quad * 4;
#pragma unroll
                for (int i = 0; i < 4; ++i) {
                    float p0 = (kb0 + 0) < SK ? exp2_fast(e[i][0]) : 0.f;
                    float p1 = (kb0 + 1) < SK ? exp2_fast(e[i][1]) : 0.f;
                    float p2 = (kb0 + 2) < SK ? exp2_fast(e[i][2]) : 0.f;
                    float p3 = (kb0 + 3) < SK ? exp2_fast(e[i][3]) : 0.f;
                    pa[i] = bc4((uint2){cvtpk(p0, p1), cvtpk(p2, p3)});
                }
            } else {
#pragma unroll
                for (int i = 0; i < 4; ++i) {
                    pa[i] = bc4((uint2){cvtpk(exp2_fast(e[i][0]), exp2_fast(e[i][1])),
                                        cvtpk(exp2_fast(e[i][2]), exp2_fast(e[i][3]))});
                }
            }
            int vbase = ((2 * t + (quad >> 1)) << 8) + (quad & 1) * 4;
            uint2 w0 = *(const uint2*)&Vl[vbase + l16 * 8];
            uint2 w1 = *(const uint2*)&Vl[vbase + (16 + l16) * 8];
            bf16x4 vb0 = bc4(w0), vb1 = bc4(w1);
#pragma unroll
            for (int i = 0; i < 4; ++i) {
                o[i][0] = pv_mfma(pa[i], vb0, o[i][0]);
                o[i][1] = pv_mfma(pa[i], vb1, o[i][1]);
                lv[i]   = pv_mfma(pa[i], ones4, lv[i]);
            }
        }
        __syncthreads();                       // drains DMA(r+1); frees buf r&1
        if (r + 2 < rounds) stage(r + 2, r & 1);
    }

    // ---- two-stage merge of 4 t-quarters via LDS (DMA quiet after final barrier) ----
    float* mg = (float*)&S[0];                 // stage1: 24KB, stage2: 12KB
    // stage 1: waves 2,3 -> waves 0,1
    {
        int slot = ((th & 1) * 64 + lane) * 48;
        if (th >= 2) {
#pragma unroll
            for (int i = 0; i < 4; ++i) {
                *(f32x4*)&mg[slot + i * 8]     = o[i][0];
                *(f32x4*)&mg[slot + i * 8 + 4] = o[i][1];
                *(f32x4*)&mg[slot + 32 + i * 4] = lv[i];
            }
        }
        __syncthreads();
        if (th < 2) {
#pragma unroll
            for (int i = 0; i < 4; ++i) {
                o[i][0] += *(const f32x4*)&mg[slot + i * 8];
                o[i][1] += *(const f32x4*)&mg[slot + i * 8 + 4];
                lv[i]   += *(const f32x4*)&mg[slot + 32 + i * 4];
            }
        }
        __syncthreads();
    }
    // stage 2: wave 1 -> wave 0
    {
        int slot = lane * 48;
        if (th == 1) {
#pragma unroll
            for (int i = 0; i < 4; ++i) {
                *(f32x4*)&mg[slot + i * 8]     = o[i][0];
                *(f32x4*)&mg[slot + i * 8 + 4] = o[i][1];
                *(f32x4*)&mg[slot + 32 + i * 4] = lv[i];
            }
        }
        __syncthreads();
        if (th == 0) {
#pragma unroll
            for (int i = 0; i < 4; ++i) {
                o[i][0] += *(const f32x4*)&mg[slot + i * 8];
                o[i][1] += *(const f32x4*)&mg[slot + i * 8 + 4];
                lv[i]   += *(const f32x4*)&mg[slot + 32 + i * 4];
            }

            // ---- cross-block 2-way merge: fp32 atomics (device-scope) ----
#pragma unroll
            for (int i = 0; i < 4; ++i) {
#pragma unroll
                for (int r2 = 0; r2 < 4; ++r2) {
                    int q = qsub + i * 16 + quad * 4 + r2;
                    size_t base = (size_t)(b * SQ + q) * 256 + h * 32;
                    atomicAdd(&out[base + l16],      o[i][0][r2]);
                    atomicAdd(&out[base + 16 + l16], o[i][1][r2]);
                    if (l16 == 0) atomicAdd(&lbuf[(b * SQ + q) * 8 + h], lv[i][r2]);
                }
            }
        }
    }
}

// ---------------- kernel 3: finalize out = gamma * O / l + x ----------------
__global__ __launch_bounds__(256) void finalize_kernel(const float* __restrict__ x,
                                                       const float* __restrict__ gammap,
                                                       const float* __restrict__ lbuf,
                                                       float* __restrict__ out) {
    int gid = blockIdx.x * 256 + threadIdx.x;   // 6272*64 threads, float4 each
    int row = gid >> 6;
    int c4  = (gid & 63) << 2;
    int h   = c4 >> 5;
    float g = gammap[0];
    float linv = g / lbuf[row * 8 + h];
    size_t base = (size_t)row * 256 + c4;
    float4 o = *(const float4*)&out[base];
    float4 xv = *(const float4*)&x[base];
    o.x = o.x * linv + xv.x;
    o.y = o.y * linv + xv.y;
    o.z = o.z * linv + xv.z;
    o.w = o.w * linv + xv.w;
    *(float4*)&out[base] = o;
}

// ---------------- launcher ----------------
extern "C" void kernel_launch(void* const* d_in, const int* in_sizes, int n_in,
                              void* d_out, int out_size, void* d_ws, size_t ws_size,
                              hipStream_t stream) {
    const float* x     = (const float*)d_in[0];
    const float* Wq    = (const float*)d_in[1];
    const float* bq    = (const float*)d_in[2];
    const float* Wk    = (const float*)d_in[3];
    const float* bk    = (const float*)d_in[4];
    const float* Wv    = (const float*)d_in[5];
    const float* bv    = (const float*)d_in[6];
    const float* gamma = (const float*)d_in[7];
    float* out = (float*)d_out;

    u16* ws   = (u16*)d_ws;
    u16* qbuf = ws + WS_Q;
    u16* kbuf = ws + WS_K;
    u16* vtb  = ws + WS_VT;
    float* lbuf = (float*)(ws + WS_LB);

    proj_kernel<<<dim3(121, 3, 2), 256, 0, stream>>>(x, Wq, Wk, Wv, bq, bk, bv,
                                                     qbuf, kbuf, vtb, out, lbuf);
    attn_kernel<<<dim3(49, 16, 2), 256, 0, stream>>>(qbuf, kbuf, vtb, out, lbuf);
    finalize_kernel<<<1568, 256, 0, stream>>>(x, gamma, lbuf, out);
}